// Round 14
// baseline (168.826 us; speedup 1.0000x reference)
//
#include <hip/hip_runtime.h>
#include <hip/hip_bf16.h>

#define N 4096
#define IND 256
#define OUTD 128
#define NEGV -9000000000000000.0f

// ---------------- Kernel A: wh = lstm_out @ W  (4096x256 @ 256x128) ----------------
__global__ __launch_bounds__(256) void wh_kernel(const float* __restrict__ x,
                                                 const float* __restrict__ W,
                                                 float* __restrict__ wh) {
    __shared__ float xs[8][IND];
    const int t = threadIdx.x;
    const int i0 = blockIdx.x * 8;
    const float4* src = (const float4*)(x + (size_t)i0 * IND);
    float4* dst = (float4*)&xs[0][0];
    dst[t] = src[t];
    dst[t + 256] = src[t + 256];
    __syncthreads();
    const int c = t & 127;
    const int rbase = (t >> 7) * 4;
    float acc[4] = {0.f, 0.f, 0.f, 0.f};
    #pragma unroll 4
    for (int k = 0; k < IND; k += 4) {
        const float w0 = W[(k + 0) * OUTD + c];
        const float w1 = W[(k + 1) * OUTD + c];
        const float w2 = W[(k + 2) * OUTD + c];
        const float w3 = W[(k + 3) * OUTD + c];
        #pragma unroll
        for (int r = 0; r < 4; ++r) {
            const float4 xv = *(const float4*)&xs[rbase + r][k];
            acc[r] = fmaf(xv.x, w0, acc[r]);
            acc[r] = fmaf(xv.y, w1, acc[r]);
            acc[r] = fmaf(xv.z, w2, acc[r]);
            acc[r] = fmaf(xv.w, w3, acc[r]);
        }
    }
    #pragma unroll
    for (int r = 0; r < 4; ++r)
        wh[(size_t)(i0 + rbase + r) * OUTD + c] = acc[r];
}

// ---------------- Kernel A2: s_i = wh @ a_i, s_j = wh @ a_j ----------------
__global__ __launch_bounds__(128) void sij_kernel(const float* __restrict__ wh,
                                                  const float* __restrict__ a,
                                                  float* __restrict__ s_i,
                                                  float* __restrict__ s_j) {
    const int i = blockIdx.x;
    const int c = threadIdx.x;
    float v = wh[(size_t)i * OUTD + c];
    float p = v * a[c];              // a_i = a[0:128]
    float q = v * a[OUTD + 5 + c];   // a_j = a[133:261]
    #pragma unroll
    for (int off = 32; off >= 1; off >>= 1) {
        p += __shfl_down(p, off);
        q += __shfl_down(q, off);
    }
    __shared__ float tmp[4];
    if ((c & 63) == 0) { tmp[c >> 6] = p; tmp[2 + (c >> 6)] = q; }
    __syncthreads();
    if (c == 0) { s_i[i] = tmp[0] + tmp[1]; s_j[i] = tmp[2] + tmp[3]; }
}

// ---------------- Kernel B: p = exp(leaky(si + e.ae + sj), diag-masked) ----------------
// ROUND-14 SPLIT, phase 1: pure HBM stream (335 MB read + 67 MB write), no LDS,
// no barriers, 16384 blocks -> every CU saturated with independent waves. exp
// without max-subtraction is exact for softmax (r13-validated: |s|<~25, f32).
// Each thread: one j-quad = 80 B contiguous edges (5x float4), sj float4, si
// scalar; diag mask -> NEGV -> exp -> 0 exactly.
__global__ __launch_bounds__(256) void se_kernel(const float* __restrict__ edges,
                                                 const float* __restrict__ s_iv,
                                                 const float* __restrict__ s_jv,
                                                 const float* __restrict__ a,
                                                 float* __restrict__ p) {
    const long long q = (long long)blockIdx.x * 256 + threadIdx.x;  // quad id
    const int i  = (int)(q >> 10);          // row = q*4 / 4096
    const int j0 = ((int)q & 1023) << 2;    // col of first elem in quad
    const float* e = edges + q * 20;
    float ef[20];
    *(float4*)&ef[0]  = *(const float4*)(e + 0);
    *(float4*)&ef[4]  = *(const float4*)(e + 4);
    *(float4*)&ef[8]  = *(const float4*)(e + 8);
    *(float4*)&ef[12] = *(const float4*)(e + 12);
    *(float4*)&ef[16] = *(const float4*)(e + 16);
    const float a0 = a[OUTD + 0], a1 = a[OUTD + 1], a2 = a[OUTD + 2],
                a3 = a[OUTD + 3], a4 = a[OUTD + 4];
    const float si = s_iv[i];
    const float4 sj = *(const float4*)(s_jv + j0);
    float ov[4];
    const float sjv[4] = {sj.x, sj.y, sj.z, sj.w};
    #pragma unroll
    for (int jj = 0; jj < 4; ++jj) {
        float d = ef[5 * jj + 4] * a4;
        d = fmaf(ef[5 * jj + 0], a0, d);
        d = fmaf(ef[5 * jj + 1], a1, d);
        d = fmaf(ef[5 * jj + 2], a2, d);
        d = fmaf(ef[5 * jj + 3], a3, d);
        float v = si + d + sjv[jj];
        v = fmaxf(v, 0.2f * v);          // leaky relu BEFORE mask (matches ref)
        if (j0 + jj == i) v = NEGV;      // diagonal -> exp -> 0
        ov[jj] = __expf(v);
    }
    float4 o; o.x = ov[0]; o.y = ov[1]; o.z = ov[2]; o.w = ov[3];
    *(float4*)(p + q * 4) = o;
}

// ---------------- Kernel C: out = (P @ wh) / rowsum(P) ----------------
// ROUND-14 SPLIT, phase 2: VALU-bound f32 matmul M=4096,N=128,K=4096.
// 512 blocks x 256 thr, BI=8 rows, BJ=128, 32 K-steps. p tile (4 KB) staged via
// ONE global_load_lds per thread into P[3] (triple buffer => ONE barrier/iter:
// stage(st+1) writes P[(st+1)%3], whose last readers finished before the
// PREVIOUS iteration's barrier). T4 counted vmcnt(17): retire stage(st) (18
// outstanding: stage(st)+16 wh+stage(st+1)) without draining stage(st+1).
// l (softmax denom) accumulated free inside PV: lacc[rr] += pp.x+..+pp.w.
// VGPR-cap model (r3/5/6/7, confirmed r8): (256,1) -> cap 256; pressure ~165.
#define BI 8
#define BJ 128
#define NSUB (N / BJ)        // 32
#define RSTR 132

#define FMA4(A, pv, wv)                  \
    A.x = fmaf(pv, wv.x, A.x);           \
    A.y = fmaf(pv, wv.y, A.y);           \
    A.z = fmaf(pv, wv.z, A.z);           \
    A.w = fmaf(pv, wv.w, A.w);

__device__ __forceinline__ void gload_lds16(const void* g, void* l) {
    __builtin_amdgcn_global_load_lds(
        (const __attribute__((address_space(1))) unsigned int*)(g),
        (__attribute__((address_space(3))) unsigned int*)(l),
        16, 0, 0);
}

__global__ __launch_bounds__(256, 1) void pv_kernel(const float* __restrict__ p,
                                                    const float* __restrict__ wh,
                                                    float* __restrict__ out) {
    __shared__ float P[3][BI * BJ];       // 12 KB, LINEAR (gload_lds-compatible)
    __shared__ float red[4][BI * RSTR];   // 16.9 KB (epilogue)
    const int t = threadIdx.x;
    const int i0 = blockIdx.x * BI;
    const int w = t >> 6;
    const int s = t & 63;
    const int cg = t & 15;
    const int c8 = cg * 8;
    const int js = t >> 4;                // j slice 0..15 (8 j each)

    // per-lane stage source: thread t covers float4 #t of the 8x128 tile:
    // row = t>>5 (32 float4 per row), rem = t&31. Lane0's LDS dest = buffer base
    // (gload_lds writes base + lane*16 -- same pattern proven rounds 8-13).
    const float* gsrc = p + (size_t)(i0 + (t >> 5)) * N + (size_t)(t & 31) * 4;

    float4 acc[BI][2];
    float lacc[BI];
    #pragma unroll
    for (int rr = 0; rr < BI; ++rr) {
        acc[rr][0] = make_float4(0.f, 0.f, 0.f, 0.f);
        acc[rr][1] = make_float4(0.f, 0.f, 0.f, 0.f);
        lacc[rr] = 0.f;
    }

    // prologue: stage tile 0, drain, barrier
    gload_lds16(gsrc, &P[0][t * 4]);
    asm volatile("s_waitcnt vmcnt(0)" ::: "memory");
    __builtin_amdgcn_s_barrier();
    __builtin_amdgcn_sched_barrier(0);

    for (int st = 0; st < NSUB; ++st) {
        const int pb = st % 3;
        const int nb = (st + 1) % 3;
        const int jb = st * BJ;

        // [A] wh(st) -> 16 float4 registers
        float4 wa[8], wb[8];
        {
            const float* whp = wh + (size_t)(jb + js * 8) * OUTD + c8;
            #pragma unroll
            for (int jj = 0; jj < 8; ++jj) {
                wa[jj] = *(const float4*)(whp + (size_t)jj * OUTD);
                wb[jj] = *(const float4*)(whp + (size_t)jj * OUTD + 4);
            }
        }
        // [D] stage next tile (clamped on last iter: redundant but keeps the
        // FIFO count uniform at 18)
        const int stn = (st + 1 < NSUB) ? (st + 1) : st;
        gload_lds16(gsrc + (size_t)stn * BJ, &P[nb][t * 4]);

        // counted wait: 18 outstanding (stage(st)+16 wh+stage(st+1)); vmcnt(17)
        // retires exactly stage(st). Barrier publishes its LDS writes.
        asm volatile("s_waitcnt vmcnt(17)" ::: "memory");
        __builtin_amdgcn_s_barrier();
        __builtin_amdgcn_sched_barrier(0);

        // PV + free l-sum
        #pragma unroll
        for (int jq = 0; jq < 2; ++jq) {
            #pragma unroll
            for (int rr = 0; rr < BI; ++rr) {
                const float4 pp = *(const float4*)&P[pb][rr * BJ + js * 8 + jq * 4];
                lacc[rr] += (pp.x + pp.y) + (pp.z + pp.w);
                FMA4(acc[rr][0], pp.x, wa[jq * 4 + 0]);
                FMA4(acc[rr][1], pp.x, wb[jq * 4 + 0]);
                FMA4(acc[rr][0], pp.y, wa[jq * 4 + 1]);
                FMA4(acc[rr][1], pp.y, wb[jq * 4 + 1]);
                FMA4(acc[rr][0], pp.z, wa[jq * 4 + 2]);
                FMA4(acc[rr][1], pp.z, wb[jq * 4 + 2]);
                FMA4(acc[rr][0], pp.w, wa[jq * 4 + 3]);
                FMA4(acc[rr][1], pp.w, wb[jq * 4 + 3]);
            }
        }
    }

    // ---- epilogue: fold js slices, combine waves, normalize ----
    #pragma unroll
    for (int rr = 0; rr < BI; ++rr) {
        #pragma unroll
        for (int h = 0; h < 2; ++h) {
            acc[rr][h].x += __shfl_xor(acc[rr][h].x, 16);
            acc[rr][h].y += __shfl_xor(acc[rr][h].y, 16);
            acc[rr][h].z += __shfl_xor(acc[rr][h].z, 16);
            acc[rr][h].w += __shfl_xor(acc[rr][h].w, 16);
            acc[rr][h].x += __shfl_xor(acc[rr][h].x, 32);
            acc[rr][h].y += __shfl_xor(acc[rr][h].y, 32);
            acc[rr][h].z += __shfl_xor(acc[rr][h].z, 32);
            acc[rr][h].w += __shfl_xor(acc[rr][h].w, 32);
        }
        lacc[rr] += __shfl_xor(lacc[rr], 16);
        lacc[rr] += __shfl_xor(lacc[rr], 32);
    }
    if (s < 16) {
        #pragma unroll
        for (int rr = 0; rr < BI; ++rr) {
            *(float4*)&red[w][rr * RSTR + c8] = acc[rr][0];
            *(float4*)&red[w][rr * RSTR + c8 + 4] = acc[rr][1];
        }
    }
    if (s == 0) {
        #pragma unroll
        for (int rr = 0; rr < BI; ++rr) red[w][rr * RSTR + 128] = lacc[rr];
    }
    __syncthreads();
    {
        const int rr = t >> 5;
        const int c4 = (t & 31) * 4;
        const float4 v0 = *(const float4*)&red[0][rr * RSTR + c4];
        const float4 v1 = *(const float4*)&red[1][rr * RSTR + c4];
        const float4 v2 = *(const float4*)&red[2][rr * RSTR + c4];
        const float4 v3 = *(const float4*)&red[3][rr * RSTR + c4];
        const float L = red[0][rr * RSTR + 128] + red[1][rr * RSTR + 128]
                      + red[2][rr * RSTR + 128] + red[3][rr * RSTR + 128];
        const float li = 1.0f / L;
        float4 o;
        o.x = (v0.x + v1.x + v2.x + v3.x) * li;
        o.y = (v0.y + v1.y + v2.y + v3.y) * li;
        o.z = (v0.z + v1.z + v2.z + v3.z) * li;
        o.w = (v0.w + v1.w + v2.w + v3.w) * li;
        *(float4*)&out[(size_t)(i0 + rr) * OUTD + c4] = o;
    }
}

extern "C" void kernel_launch(void* const* d_in, const int* in_sizes, int n_in,
                              void* d_out, int out_size, void* d_ws, size_t ws_size,
                              hipStream_t stream) {
    // inputs: 0=ids(int, unused), 1=lstm_out, 2=edges_list, 3=W, 4=a, 5=first(unused)
    const float* lstm_out = (const float*)d_in[1];
    const float* edges    = (const float*)d_in[2];
    const float* W        = (const float*)d_in[3];
    const float* a        = (const float*)d_in[4];
    float* out = (float*)d_out;

    float* wh  = (float*)d_ws;                  // 4096*128 f32 = 2 MB
    float* s_i = wh + (size_t)N * OUTD;         // 4096
    float* s_j = s_i + N;                       // 4096
    float* pbuf = s_j + N;                      // 4096*4096 f32 = 67 MB

    wh_kernel<<<N / 8, 256, 0, stream>>>(lstm_out, W, wh);
    sij_kernel<<<N, 128, 0, stream>>>(wh, a, s_i, s_j);
    se_kernel<<<(N * (N / 4)) / 256, 256, 0, stream>>>(edges, s_i, s_j, a, pbuf);
    pv_kernel<<<N / BI, 256, 0, stream>>>(pbuf, wh, out);
}

// Round 15
// 91.257 us; speedup vs baseline: 1.8500x; 1.8500x over previous
//
#include <hip/hip_runtime.h>
#include <hip/hip_bf16.h>

#define N 4096
#define IND 256
#define OUTD 128
#define NEGV -9000000000000000.0f

typedef __attribute__((ext_vector_type(8))) short bf16x8;
typedef __attribute__((ext_vector_type(4))) float f32x4;

static __device__ __forceinline__ unsigned short f2bf(float x) {
    unsigned int u = __float_as_uint(x);
    u = (u + 0x7FFFu + ((u >> 16) & 1u)) >> 16;   // round-nearest-even
    return (unsigned short)u;
}

// ---------------- Kernel A: wh = lstm_out @ W  (4096x256 @ 256x128) ----------------
__global__ __launch_bounds__(256) void wh_kernel(const float* __restrict__ x,
                                                 const float* __restrict__ W,
                                                 float* __restrict__ wh) {
    __shared__ float xs[8][IND];
    const int t = threadIdx.x;
    const int i0 = blockIdx.x * 8;
    const float4* src = (const float4*)(x + (size_t)i0 * IND);
    float4* dst = (float4*)&xs[0][0];
    dst[t] = src[t];
    dst[t + 256] = src[t + 256];
    __syncthreads();
    const int c = t & 127;
    const int rbase = (t >> 7) * 4;
    float acc[4] = {0.f, 0.f, 0.f, 0.f};
    #pragma unroll 4
    for (int k = 0; k < IND; k += 4) {
        const float w0 = W[(k + 0) * OUTD + c];
        const float w1 = W[(k + 1) * OUTD + c];
        const float w2 = W[(k + 2) * OUTD + c];
        const float w3 = W[(k + 3) * OUTD + c];
        #pragma unroll
        for (int r = 0; r < 4; ++r) {
            const float4 xv = *(const float4*)&xs[rbase + r][k];
            acc[r] = fmaf(xv.x, w0, acc[r]);
            acc[r] = fmaf(xv.y, w1, acc[r]);
            acc[r] = fmaf(xv.z, w2, acc[r]);
            acc[r] = fmaf(xv.w, w3, acc[r]);
        }
    }
    #pragma unroll
    for (int r = 0; r < 4; ++r)
        wh[(size_t)(i0 + rbase + r) * OUTD + c] = acc[r];
}

// ---------------- Kernel A2: s_i = wh @ a_i, s_j = wh @ a_j ----------------
__global__ __launch_bounds__(128) void sij_kernel(const float* __restrict__ wh,
                                                  const float* __restrict__ a,
                                                  float* __restrict__ s_i,
                                                  float* __restrict__ s_j) {
    const int i = blockIdx.x;
    const int c = threadIdx.x;
    float v = wh[(size_t)i * OUTD + c];
    float p = v * a[c];              // a_i = a[0:128]
    float q = v * a[OUTD + 5 + c];   // a_j = a[133:261]
    #pragma unroll
    for (int off = 32; off >= 1; off >>= 1) {
        p += __shfl_down(p, off);
        q += __shfl_down(q, off);
    }
    __shared__ float tmp[4];
    if ((c & 63) == 0) { tmp[c >> 6] = p; tmp[2 + (c >> 6)] = q; }
    __syncthreads();
    if (c == 0) { s_i[i] = tmp[0] + tmp[1]; s_j[i] = tmp[2] + tmp[3]; }
}

// ---------------- Kernel A3: whT[c][j] = bf16(wh[j][c])  (B-operand layout) ----------------
// 64 blocks x 256 thr; LDS transpose; coalesced read AND write (wave-contiguous).
__global__ __launch_bounds__(256) void whT_kernel(const float* __restrict__ wh,
                                                  unsigned short* __restrict__ whT) {
    __shared__ float ls[64][130];   // +2 pad: phase-2 read stride 130 -> 2-way banks
    const int t = threadIdx.x;
    const int j0 = blockIdx.x * 64;
    #pragma unroll
    for (int k = 0; k < 32; ++k) {
        const int idx = k * 256 + t;
        const int j = idx >> 7;
        const int c = idx & 127;
        ls[j][c] = wh[(size_t)(j0 + j) * OUTD + c];
    }
    __syncthreads();
    #pragma unroll
    for (int k = 0; k < 32; ++k) {
        const int idx = k * 256 + t;
        const int c = idx >> 6;       // constant per wave -> 128B contiguous store
        const int j = idx & 63;
        whT[(size_t)c * N + j0 + j] = f2bf(ls[j][c]);
    }
}

// ---------------- Kernel B: flash GAT with MFMA PV ----------------
// ROUND-15: r13's slot (~8200 cyc) = HBM 4000 + VALU 2450 + LDS 2600, pipes
// serializing; only cutting the sum helps. PV f32 FMA (2048 cyc/SIMD/iter) ->
// mfma_f32_16x16x32_bf16 (4 MFMA/wave/iter ~ 40 cyc) + PV LDS reads 16->2 b128.
// Shape: BI=16 (MFMA M), BJ=64, NCH=2 j-chunks -> grid 512, 2 blocks/CU.
// Fragments: A = P[16 rows][64 k] bf16 in LDS, stride 72 (144B: 16B-aligned
//   b128 A-reads, 2-way banks = free). lane: row=L&15, k=(L>>4)*8+q [m89 layout].
// B = whT[col][k] bf16 from GLOBAL (L2, 1 MB) straight to regs: lane col=L&15,
//   8 contig k. Wave w owns cols [32w,32w+32) = 2 16-col tiles; D: col=L&15,
//   row=(L>>4)*4+reg -> no cross-wave acc reduction at all.
// Sync skeleton = r13 verbatim: [A] B-frags+sj(st+1)->regs, sched_barrier;
// [C] scores(st) E[b0]->P[pb] (p=exp(s) direct, r13-validated); [D] STAGE(st+2);
// [E] lgkmcnt(0)+barrier; [F] MFMA (compiler emits vmcnt(6): retires stage(st+1),
// leaves stage(st+2) in flight = T4 counted); [G] barrier (publishes stage).
// Raw partials + per-chunk l; merge divides. VGPR ~90 under (256,1) cap 256.
#define BI 16
#define BJ 64
#define NCH 2
#define CHJ (N / NCH)          // 2048
#define NSUB (CHJ / BJ)        // 32
#define PPAD 72                // P row stride in bf16 (144 B)
#define EFLOATS (BI * BJ * 5)  // 5120 floats = 20 KB per buffer

__device__ __forceinline__ void gload_lds16(const void* g, void* l) {
    __builtin_amdgcn_global_load_lds(
        (const __attribute__((address_space(1))) unsigned int*)(g),
        (__attribute__((address_space(3))) unsigned int*)(l),
        16, 0, 0);
}

__global__ __launch_bounds__(256, 1) void gat_mfma(const float* __restrict__ edges,
                                                   const unsigned short* __restrict__ whT,
                                                   const float* __restrict__ s_iv,
                                                   const float* __restrict__ s_jv,
                                                   const float* __restrict__ a,
                                                   float* __restrict__ part,
                                                   float* __restrict__ lout) {
    __shared__ float E[3][EFLOATS];              // 60 KB
    __shared__ unsigned short P[2][BI * PPAD];   // 4.6 KB

    const int t = threadIdx.x;
    const int ib = blockIdx.x & 255;
    const int ch = blockIdx.x >> 8;
    const int i0 = ib * BI;
    const int jbase = ch * CHJ;
    const int w = t >> 6;
    const int s = t & 63;
    const int lhi = s >> 4;    // lane>>4 within wave (0..3)
    const int llo = s & 15;    // lane&15

    const float ae0 = a[OUTD + 0], ae1 = a[OUTD + 1], ae2 = a[OUTD + 2],
                ae3 = a[OUTD + 3], ae4 = a[OUTD + 4];
    float si[4];
    #pragma unroll
    for (int rr = 0; rr < 4; ++rr) si[rr] = s_iv[i0 + 4 * w + rr];

    // Stage sources: float4 f = k*256+t of the 1280-float4 (16x64x5) tile;
    // row = f/80, rem = f%80 are subtile-invariant; jbase folded into base ptr.
    const char* g0; const char* g1; const char* g2; const char* g3; const char* g4;
    {
        const char* eb = (const char*)edges + (size_t)jbase * 20;
        #define MKG(K, VAR)                                                    \
        {   const int f = K * 256 + t;                                         \
            const int row = f / 80;                                            \
            const int rem = f - row * 80;                                      \
            VAR = eb + (size_t)(i0 + row) * (N * 20) + (size_t)rem * 16; }
        MKG(0, g0) MKG(1, g1) MKG(2, g2) MKG(3, g3) MKG(4, g4)
        #undef MKG
    }
    #define STAGE(BB, ST)                                                      \
    {   const size_t jo = (size_t)(ST) * (BJ * 20);                            \
        gload_lds16(g0 + jo, &E[BB][(0 * 256 + t) * 4]);                       \
        gload_lds16(g1 + jo, &E[BB][(1 * 256 + t) * 4]);                       \
        gload_lds16(g2 + jo, &E[BB][(2 * 256 + t) * 4]);                       \
        gload_lds16(g3 + jo, &E[BB][(3 * 256 + t) * 4]);                       \
        gload_lds16(g4 + jo, &E[BB][(4 * 256 + t) * 4]); }

    f32x4 acc0 = {0.f, 0.f, 0.f, 0.f};
    f32x4 acc1 = {0.f, 0.f, 0.f, 0.f};
    float lac[4] = {0.f, 0.f, 0.f, 0.f};

    // B-operand row pointers: tile0 col = 32w+llo, tile1 col = 32w+16+llo
    const unsigned short* wt0 = whT + (size_t)(w * 32 + llo) * N;
    const unsigned short* wt1 = wt0 + (size_t)16 * N;

    // ---- prologue: sj(0), stage(0), stage(1); retire sj+stage0 only ----
    float sj = s_jv[jbase + s];
    STAGE(0, 0)
    STAGE(1, 1)
    asm volatile("s_waitcnt vmcnt(5)" ::: "memory");
    __builtin_amdgcn_s_barrier();

    int b0 = 0, b1 = 1, b2 = 2;
    for (int st = 0; st < NSUB; ++st) {
        const int pb = st & 1;
        const int jb = jbase + st * BJ;   // absolute j of subtile start

        // ---- [A] B-fragments(st) + sj(st+1) -> regs, BEFORE this iter's stage ----
        const int kof = jb + lhi * 8;
        const bf16x8 B00 = *(const bf16x8*)(wt0 + kof);
        const bf16x8 B01 = *(const bf16x8*)(wt0 + kof + 32);
        const bf16x8 B10 = *(const bf16x8*)(wt1 + kof);
        const bf16x8 B11 = *(const bf16x8*)(wt1 + kof + 32);
        float sj_nx = 0.f;
        if (st + 1 < NSUB) sj_nx = s_jv[jb + BJ + s];
        __builtin_amdgcn_sched_barrier(0);

        // ---- [C] scores(st): p = exp(s) direct (r13-validated), bf16 -> P ----
        {
            const float* Eb = &E[b0][0];
            #pragma unroll
            for (int rr = 0; rr < 4; ++rr) {
                const int row = 4 * w + rr;
                const int e = row * 320 + s * 5;
                float d = Eb[e + 4] * ae4;
                d = fmaf(Eb[e + 0], ae0, d);
                d = fmaf(Eb[e + 1], ae1, d);
                d = fmaf(Eb[e + 2], ae2, d);
                d = fmaf(Eb[e + 3], ae3, d);
                float v = si[rr] + d + sj;
                v = fmaxf(v, 0.2f * v);             // leaky relu before mask
                if (jb + s == i0 + row) v = NEGV;   // diag -> exp -> 0
                const float p = __expf(v);
                lac[rr] += p;
                P[pb][row * PPAD + s] = f2bf(p);
            }
        }

        // ---- [D] stage st+2 into E[b2] ----
        if (st + 2 < NSUB) {
            STAGE(b2, st + 2)
        }

        // ---- [E] LDS-only barrier: P visible; stages stay in flight ----
        asm volatile("s_waitcnt lgkmcnt(0)" ::: "memory");
        __builtin_amdgcn_s_barrier();
        asm volatile("" ::: "memory");

        // ---- [F] MFMA PV: A from P (b128 x2), B from regs ----
        {
            const unsigned short* Pb = &P[pb][0];
            const bf16x8 A0 = *(const bf16x8*)(Pb + llo * PPAD + lhi * 8);
            const bf16x8 A1 = *(const bf16x8*)(Pb + llo * PPAD + 32 + lhi * 8);
            acc0 = __builtin_amdgcn_mfma_f32_16x16x32_bf16(A0, B00, acc0, 0, 0, 0);
            acc1 = __builtin_amdgcn_mfma_f32_16x16x32_bf16(A0, B10, acc1, 0, 0, 0);
            acc0 = __builtin_amdgcn_mfma_f32_16x16x32_bf16(A1, B01, acc0, 0, 0, 0);
            acc1 = __builtin_amdgcn_mfma_f32_16x16x32_bf16(A1, B11, acc1, 0, 0, 0);
        }

        // ---- [G] rotate; plain barrier (publishes stage retirement; NO drain) ----
        sj = sj_nx;
        __builtin_amdgcn_s_barrier();
        const int tb = b0; b0 = b1; b1 = b2; b2 = tb;
    }

    // ---- epilogue: reduce l once; write raw partials (merge normalizes) ----
    #pragma unroll
    for (int rr = 0; rr < 4; ++rr) {
        #pragma unroll
        for (int off = 32; off >= 1; off >>= 1)
            lac[rr] += __shfl_xor(lac[rr], off);
    }
    if (s == 0) {
        #pragma unroll
        for (int rr = 0; rr < 4; ++rr)
            lout[(size_t)ch * N + i0 + 4 * w + rr] = lac[rr];
    }
    #pragma unroll
    for (int reg = 0; reg < 4; ++reg) {
        const int row = lhi * 4 + reg;          // D row = (lane>>4)*4 + reg
        float* pr = part + ((size_t)ch * N + (i0 + row)) * OUTD + w * 32 + llo;
        pr[0]  = acc0[reg];
        pr[16] = acc1[reg];
    }
}

// ---------------- Kernel C: merge the 2 chunk partials ----------------
__global__ __launch_bounds__(256) void gat_merge(const float* __restrict__ part,
                                                 const float* __restrict__ lout,
                                                 float* __restrict__ out) {
    const int idx = blockIdx.x * 256 + threadIdx.x;   // over N*OUTD
    const int i = idx >> 7;
    const float L = lout[i] + lout[N + i];
    out[idx] = (part[idx] + part[(size_t)N * OUTD + idx]) / L;
}

extern "C" void kernel_launch(void* const* d_in, const int* in_sizes, int n_in,
                              void* d_out, int out_size, void* d_ws, size_t ws_size,
                              hipStream_t stream) {
    // inputs: 0=ids(int, unused), 1=lstm_out, 2=edges_list, 3=W, 4=a, 5=first(unused)
    const float* lstm_out = (const float*)d_in[1];
    const float* edges    = (const float*)d_in[2];
    const float* W        = (const float*)d_in[3];
    const float* a        = (const float*)d_in[4];
    float* out = (float*)d_out;

    float* wh   = (float*)d_ws;                        // 4096*128 f32
    float* s_i  = wh + (size_t)N * OUTD;               // 4096
    float* s_j  = s_i + N;                             // 4096
    float* lout = s_j + N;                             // 2*4096
    float* part = lout + (size_t)NCH * N;              // 2*4096*128 f32 (4 MB)
    unsigned short* whT = (unsigned short*)(part + (size_t)NCH * N * OUTD); // 128*4096 bf16 (1 MB)

    wh_kernel<<<N / 8, 256, 0, stream>>>(lstm_out, W, wh);
    sij_kernel<<<N, 128, 0, stream>>>(wh, a, s_i, s_j);
    whT_kernel<<<N / 64, 256, 0, stream>>>(wh, whT);
    gat_mfma<<<256 * NCH, 256, 0, stream>>>(edges, whT, s_i, s_j, a, part, lout);
    gat_merge<<<(N * OUTD) / 256, 256, 0, stream>>>(part, lout, out);
}